// Round 4
// baseline (122.549 us; speedup 1.0000x reference)
//
#include <hip/hip_runtime.h>
#include <math.h>

#define OUT_F      4096
#define IN_F       4096
#define NUM_CHUNKS 16384
#define CHUNK_SIZE 1024
#define D_ALPHA    64
#define HIDDEN     256
#define TOKENS     256
#define ZY         8     // split-K for Y gemm

typedef __attribute__((ext_vector_type(8))) __bf16 bf16x8;
typedef __attribute__((ext_vector_type(4))) __bf16 bf16x4;
typedef __attribute__((ext_vector_type(4))) float f32x4;

__device__ __forceinline__ void gl2lds16(const void* g, void* l) {
    __builtin_amdgcn_global_load_lds(
        (const __attribute__((address_space(1))) void*)g,
        (__attribute__((address_space(3))) void*)l,
        16, 0, 0);
}

// ============ K1: fused prep ================================================
// blocks [0,2048)      : H = gelu(codebook @ w1^T + b1) -> bf16, 8 chunks/blk
// blocks [2048,2304)   : x fp32->bf16 + xb2[t] = dot(x[t], tile(b2))
// blocks [2304,2560)   : w2 (1024x256) -> w2t bf16 (256x1024)
__global__ __launch_bounds__(256) void prep_kernel(
    const float* __restrict__ cb, const float* __restrict__ w1,
    const float* __restrict__ b1, const float* __restrict__ x,
    const float* __restrict__ b2, const float* __restrict__ w2,
    __bf16* __restrict__ H, __bf16* __restrict__ xb,
    float* __restrict__ xb2, __bf16* __restrict__ w2t) {
    __shared__ char smem[32 * 33 * 4];
    const int b   = blockIdx.x;
    const int tid = threadIdx.x;

    if (b < 2048) {
        // ---- hidden ----
        float* sa = (float*)smem;                       // 8*64 floats
        const int c0 = b * 8;
        sa[tid]       = cb[(size_t)c0 * 64 + tid];
        sa[tid + 256] = cb[(size_t)c0 * 64 + tid + 256];
        __syncthreads();
        float4 w[16];
        const float4* w1r = reinterpret_cast<const float4*>(w1 + tid * 64);
#pragma unroll
        for (int q = 0; q < 16; ++q) w[q] = w1r[q];
        const float bias1 = b1[tid];
#pragma unroll
        for (int c = 0; c < 8; ++c) {
            float acc = bias1;
            const float4* sav = reinterpret_cast<const float4*>(sa + c * 64);
#pragma unroll
            for (int q = 0; q < 16; ++q) {
                float4 a4 = sav[q];
                acc += a4.x * w[q].x + a4.y * w[q].y + a4.z * w[q].z + a4.w * w[q].w;
            }
            float g = 0.5f * acc * (1.0f + erff(acc * 0.70710678118654752f));
            H[(size_t)(c0 + c) * 256 + tid] = (__bf16)g;
        }
    } else if (b < 2304) {
        // ---- x convert + row dot with tiled b2 ----
        float* ws_ = (float*)smem;
        const int t = b - 2048;
        const float4* xr  = reinterpret_cast<const float4*>(x + (size_t)t * IN_F);
        const float4* b24 = reinterpret_cast<const float4*>(b2);
        bf16x4* xb4 = reinterpret_cast<bf16x4*>(xb + (size_t)t * IN_F);
        float acc = 0.0f;
#pragma unroll
        for (int ii = 0; ii < 4; ++ii) {
            const int idx = ii * 256 + tid;
            float4 v = xr[idx];
            bf16x4 o;
            o.x = (__bf16)v.x; o.y = (__bf16)v.y; o.z = (__bf16)v.z; o.w = (__bf16)v.w;
            xb4[idx] = o;
            float4 bb = b24[idx & 255];
            acc += v.x * bb.x + v.y * bb.y + v.z * bb.z + v.w * bb.w;
        }
#pragma unroll
        for (int off = 32; off > 0; off >>= 1) acc += __shfl_down(acc, off, 64);
        if ((tid & 63) == 0) ws_[tid >> 6] = acc;
        __syncthreads();
        if (tid == 0) xb2[t] = ws_[0] + ws_[1] + ws_[2] + ws_[3];
    } else {
        // ---- w2 transpose -> bf16 ----
        float (*tile)[33] = (float (*)[33])smem;
        const int bb = b - 2304;
        const int h0 = (bb & 7) * 32;          // HIDDEN/32 = 8
        const int p0 = (bb >> 3) * 32;
        const int r = tid >> 5;
        const int c = tid & 31;
#pragma unroll
        for (int ii = 0; ii < 4; ++ii)
            tile[r + 8 * ii][c] = w2[(size_t)(p0 + r + 8 * ii) * HIDDEN + h0 + c];
        __syncthreads();
#pragma unroll
        for (int ii = 0; ii < 4; ++ii)
            w2t[(size_t)(h0 + r + 8 * ii) * CHUNK_SIZE + p0 + c] =
                (__bf16)tile[c][r + 8 * ii];
    }
}

// ============ double-buffered bf16 MFMA GEMM ================================
// C_part = A[M][K] @ B[N][K]^T over k-slice [z*kps, (z+1)*kps)
// 128x128 tile, BK=32, 256 thr = 4 waves (2x2), wave = 64x64 = 4x4 mfma.
// EPI 0: fp32 partial at z offset.  EPI 1: fp32 final += bias[col]+rowterm[row].
template <int EPI>
__global__ __launch_bounds__(256) void gemm_bt_mfma(
    const __bf16* __restrict__ A, const __bf16* __restrict__ B,
    const float* __restrict__ bias, const float* __restrict__ rowterm,
    float* __restrict__ C, int M, int N, int K, int k_per_split) {
    constexpr int BK = 32;
    __shared__ __bf16 sA[2 * 128 * BK];
    __shared__ __bf16 sB[2 * 128 * BK];

    const int tid = threadIdx.x;
    const int m0 = blockIdx.y * 128;
    const int n0 = blockIdx.x * 128;
    const int kz0 = blockIdx.z * k_per_split;
    const int kz1 = kz0 + k_per_split;

    const int srow = tid >> 2;
    const int scol = (tid & 3) * 8;
    const __bf16* gA0 = A + (size_t)(m0 + srow) * K + scol;
    const __bf16* gA1 = A + (size_t)(m0 + srow + 64) * K + scol;
    const __bf16* gB0 = B + (size_t)(n0 + srow) * K + scol;
    const __bf16* gB1 = B + (size_t)(n0 + srow + 64) * K + scol;

    const int wave = tid >> 6;
    const int lane = tid & 63;
    const int wm = (wave & 1) * 64;
    const int wn = (wave >> 1) * 64;
    const int fr = lane & 15;
    const int fq = lane >> 4;
    const int aoff = (wm + fr) * BK + fq * 8;
    const int boff = (wn + fr) * BK + fq * 8;

    f32x4 acc[4][4] = {};

    // prologue: stage k0 into buffer 0
    {
        __bf16* lA = sA + tid * 8;
        __bf16* lB = sB + tid * 8;
        gl2lds16(gA0 + kz0, lA);
        gl2lds16(gA1 + kz0, lA + 2048);
        gl2lds16(gB0 + kz0, lB);
        gl2lds16(gB1 + kz0, lB + 2048);
    }

    int cur = 0;
    for (int k0 = kz0; k0 < kz1; k0 += BK) {
        __syncthreads();   // drains vmcnt: buffer `cur` is ready

        // prefetch next tile into the other buffer (overlaps with MFMA below)
        const int nk = k0 + BK;
        if (nk < kz1) {
            const int nb = cur ^ 1;
            __bf16* lA = sA + nb * 4096 + tid * 8;
            __bf16* lB = sB + nb * 4096 + tid * 8;
            gl2lds16(gA0 + nk, lA);
            gl2lds16(gA1 + nk, lA + 2048);
            gl2lds16(gB0 + nk, lB);
            gl2lds16(gB1 + nk, lB + 2048);
        }

        const __bf16* cA = sA + cur * 4096;
        const __bf16* cB = sB + cur * 4096;
        bf16x8 af[4], bfr[4];
#pragma unroll
        for (int i = 0; i < 4; ++i) {
            af[i]  = *reinterpret_cast<const bf16x8*>(cA + aoff + i * 16 * BK);
            bfr[i] = *reinterpret_cast<const bf16x8*>(cB + boff + i * 16 * BK);
        }
#pragma unroll
        for (int i = 0; i < 4; ++i)
#pragma unroll
            for (int j = 0; j < 4; ++j)
                acc[i][j] = __builtin_amdgcn_mfma_f32_16x16x32_bf16(
                    af[i], bfr[j], acc[i][j], 0, 0, 0);
        cur ^= 1;
    }

    const size_t zoff = (EPI == 0) ? (size_t)blockIdx.z * (size_t)M * N : 0;
#pragma unroll
    for (int j = 0; j < 4; ++j) {
        const int col = n0 + wn + j * 16 + fr;
        const float bv = (EPI == 1) ? bias[col] : 0.0f;
#pragma unroll
        for (int i = 0; i < 4; ++i) {
            const int rbase = m0 + wm + i * 16 + fq * 4;
#pragma unroll
            for (int r = 0; r < 4; ++r) {
                float v = acc[i][j][r] + bv;
                if (EPI == 1) v += rowterm[rbase + r];
                C[zoff + (size_t)(rbase + r) * N + col] = v;
            }
        }
    }
}

// ============ K3: reduce Y partials -> bf16 Y ===============================
__global__ __launch_bounds__(256) void reduce_y(
    const float* __restrict__ part, __bf16* __restrict__ Y) {
    const int i = blockIdx.x * blockDim.x + threadIdx.x;   // float4 idx
    const int n4 = 1024 * HIDDEN / 4;
    if (i >= n4) return;
    float4 s = {0, 0, 0, 0};
#pragma unroll
    for (int z = 0; z < ZY; ++z) {
        float4 p = reinterpret_cast<const float4*>(part + (size_t)z * 1024 * HIDDEN)[i];
        s.x += p.x; s.y += p.y; s.z += p.z; s.w += p.w;
    }
    bf16x4 o;
    o.x = (__bf16)s.x; o.y = (__bf16)s.y; o.z = (__bf16)s.z; o.w = (__bf16)s.w;
    reinterpret_cast<bf16x4*>(Y)[i] = o;
}

extern "C" void kernel_launch(void* const* d_in, const int* in_sizes, int n_in,
                              void* d_out, int out_size, void* d_ws, size_t ws_size,
                              hipStream_t stream) {
    const float* x        = (const float*)d_in[0];
    const float* codebook = (const float*)d_in[1];
    const float* w1       = (const float*)d_in[2];
    const float* b1       = (const float*)d_in[3];
    const float* w2       = (const float*)d_in[4];
    const float* b2       = (const float*)d_in[5];
    const float* bias     = (const float*)d_in[6];
    float* out = (float*)d_out;

    // ws layout (MB offsets):
    //   xb   bf16 256x4096       2 MB @ 0
    //   w2t  bf16 256x1024      .5 MB @ 2
    //   H    bf16 16384x256      8 MB @ 3
    //   Y    bf16 1024x256      .5 MB @ 11
    //   xb2  fp32 256            1 KB @ 12
    //   Yp   fp32 ZY x 1024x256  8 MB @ 13
    char* ws = (char*)d_ws;
    __bf16* xb  = (__bf16*)(ws);
    __bf16* w2t = (__bf16*)(ws + (2u << 20));
    __bf16* H   = (__bf16*)(ws + (3u << 20));
    __bf16* Y   = (__bf16*)(ws + (11u << 20));
    float*  xb2 = (float*)(ws + (12u << 20));
    float*  Yp  = (float*)(ws + (13u << 20));

    // K1: all prep (hidden + x-cvt/rowdot + w2 transpose)
    prep_kernel<<<2560, 256, 0, stream>>>(codebook, w1, b1, x, b2, w2,
                                          H, xb, xb2, w2t);

    // K2: Y partials = xr(1024x1024) @ w2t^T   (M=1024,N=256,K=1024), ZY-split
    {
        dim3 grid(HIDDEN / 128, 1024 / 128, ZY);
        gemm_bt_mfma<0><<<grid, 256, 0, stream>>>(
            xb, w2t, nullptr, nullptr, Yp, 1024, HIDDEN, 1024, 1024 / ZY);
    }

    // K3: reduce Y partials -> bf16 Y
    reduce_y<<<(1024 * HIDDEN / 4) / 256, 256, 0, stream>>>(Yp, Y);

    // K4: out = Ycat(256x1024) @ Hflat^T + bias[col] + xb2[row]
    {
        dim3 grid(OUT_F / 128, TOKENS / 128, 1);
        gemm_bt_mfma<1><<<grid, 256, 0, stream>>>(
            Y, H, bias, xb2, out, TOKENS, OUT_F, 1024, 1024);
    }
}

// Round 5
// 114.391 us; speedup vs baseline: 1.0713x; 1.0713x over previous
//
#include <hip/hip_runtime.h>
#include <math.h>

#define OUT_F      4096
#define IN_F       4096
#define NUM_CHUNKS 16384
#define CHUNK_SIZE 1024
#define D_ALPHA    64
#define HIDDEN     256
#define TOKENS     256
#define ZY         4     // split-K for Y gemm

typedef __attribute__((ext_vector_type(8))) __bf16 bf16x8;
typedef __attribute__((ext_vector_type(4))) __bf16 bf16x4;
typedef __attribute__((ext_vector_type(4))) float f32x4;

__device__ __forceinline__ void gl2lds16(const void* g, void* l) {
    __builtin_amdgcn_global_load_lds(
        (const __attribute__((address_space(1))) void*)g,
        (__attribute__((address_space(3))) void*)l,
        16, 0, 0);
}

// ============ K1: fused prep ================================================
// blocks [0,512)    : H = gelu(codebook @ w1^T + b1) -> bf16, 32 chunks/blk
// blocks [512,768)  : x fp32->bf16 + xb2[t] = dot(x[t], tile(b2))
// blocks [768,1024) : w2 (1024x256) -> w2t bf16 (256x1024)
__global__ __launch_bounds__(256) void prep_kernel(
    const float* __restrict__ cb, const float* __restrict__ w1,
    const float* __restrict__ b1, const float* __restrict__ x,
    const float* __restrict__ b2, const float* __restrict__ w2,
    __bf16* __restrict__ H, __bf16* __restrict__ xb,
    float* __restrict__ xb2, __bf16* __restrict__ w2t) {
    __shared__ char smem[32 * 64 * 4];     // 8 KB, reused per branch
    const int b   = blockIdx.x;
    const int tid = threadIdx.x;

    if (b < 512) {
        // ---- hidden: 32 chunks per block (w1 read once per 32 chunks) ----
        float* sa = (float*)smem;                       // 32*64 floats
        const int c0 = b * 32;
        {
            const float4* cb4 = reinterpret_cast<const float4*>(cb) + (size_t)b * 512;
            float4* sa4 = reinterpret_cast<float4*>(sa);
            sa4[tid]       = cb4[tid];
            sa4[tid + 256] = cb4[tid + 256];
        }
        __syncthreads();
        float4 w[16];
        const float4* w1r = reinterpret_cast<const float4*>(w1 + tid * 64);
#pragma unroll
        for (int q = 0; q < 16; ++q) w[q] = w1r[q];
        const float bias1 = b1[tid];
        for (int c = 0; c < 32; ++c) {
            float acc = bias1;
            const float4* sav = reinterpret_cast<const float4*>(sa + c * 64);
#pragma unroll
            for (int q = 0; q < 16; ++q) {
                float4 a4 = sav[q];
                acc += a4.x * w[q].x + a4.y * w[q].y + a4.z * w[q].z + a4.w * w[q].w;
            }
            float g = 0.5f * acc * (1.0f + erff(acc * 0.70710678118654752f));
            H[(size_t)(c0 + c) * 256 + tid] = (__bf16)g;
        }
    } else if (b < 768) {
        // ---- x convert + row dot with tiled b2 ----
        float* ws_ = (float*)smem;
        const int t = b - 512;
        const float4* xr  = reinterpret_cast<const float4*>(x + (size_t)t * IN_F);
        const float4* b24 = reinterpret_cast<const float4*>(b2);
        bf16x4* xb4 = reinterpret_cast<bf16x4*>(xb + (size_t)t * IN_F);
        float acc = 0.0f;
#pragma unroll
        for (int ii = 0; ii < 4; ++ii) {
            const int idx = ii * 256 + tid;
            float4 v = xr[idx];
            bf16x4 o;
            o.x = (__bf16)v.x; o.y = (__bf16)v.y; o.z = (__bf16)v.z; o.w = (__bf16)v.w;
            xb4[idx] = o;
            float4 bb = b24[idx & 255];
            acc += v.x * bb.x + v.y * bb.y + v.z * bb.z + v.w * bb.w;
        }
#pragma unroll
        for (int off = 32; off > 0; off >>= 1) acc += __shfl_down(acc, off, 64);
        if ((tid & 63) == 0) ws_[tid >> 6] = acc;
        __syncthreads();
        if (tid == 0) xb2[t] = ws_[0] + ws_[1] + ws_[2] + ws_[3];
    } else {
        // ---- w2 transpose -> bf16 ----
        float (*tile)[33] = (float (*)[33])smem;
        const int bb = b - 768;
        const int h0 = (bb & 7) * 32;          // HIDDEN/32 = 8
        const int p0 = (bb >> 3) * 32;
        const int r = tid >> 5;
        const int c = tid & 31;
#pragma unroll
        for (int ii = 0; ii < 4; ++ii)
            tile[r + 8 * ii][c] = w2[(size_t)(p0 + r + 8 * ii) * HIDDEN + h0 + c];
        __syncthreads();
#pragma unroll
        for (int ii = 0; ii < 4; ++ii)
            w2t[(size_t)(h0 + r + 8 * ii) * CHUNK_SIZE + p0 + c] =
                (__bf16)tile[c][r + 8 * ii];
    }
}

// ============ bf16 MFMA GEMM, 64x64 tile, BK=64 =============================
// C_part = A[M][K] @ B[N][K]^T over k-slice [z*kps, (z+1)*kps)
// 256 thr = 4 waves (2x2), wave = 32x32 = 2x2 mfma tiles, 2 k-steps/iter.
// EPI 0: fp32 partial at z offset.  EPI 1: fp32 final += bias[col]+rowterm[row].
template <int EPI>
__global__ __launch_bounds__(256) void gemm_bt_mfma64(
    const __bf16* __restrict__ A, const __bf16* __restrict__ B,
    const float* __restrict__ bias, const float* __restrict__ rowterm,
    float* __restrict__ C, int M, int N, int K, int k_per_split) {
    constexpr int BK = 64;
    __shared__ __bf16 sA[64 * BK];   // 8 KB
    __shared__ __bf16 sB[64 * BK];

    const int tid = threadIdx.x;
    const int m0 = blockIdx.y * 64;
    const int n0 = blockIdx.x * 64;
    const int kz0 = blockIdx.z * k_per_split;
    const int kz1 = kz0 + k_per_split;

    // staging: thread t -> 16B at flat el t*8 (rows 0..31), +2048 (rows 32..63)
    const int srow = tid >> 3;            // 0..31
    const int scol = (tid & 7) * 8;       // 0..56
    const __bf16* gA0 = A + (size_t)(m0 + srow) * K + scol;
    const __bf16* gA1 = A + (size_t)(m0 + srow + 32) * K + scol;
    const __bf16* gB0 = B + (size_t)(n0 + srow) * K + scol;
    const __bf16* gB1 = B + (size_t)(n0 + srow + 32) * K + scol;
    __bf16* lA0 = sA + tid * 8;
    __bf16* lA1 = sA + tid * 8 + 2048;
    __bf16* lB0 = sB + tid * 8;
    __bf16* lB1 = sB + tid * 8 + 2048;

    const int wave = tid >> 6;
    const int lane = tid & 63;
    const int wm = (wave & 1) * 32;
    const int wn = (wave >> 1) * 32;
    const int fr = lane & 15;
    const int fq = lane >> 4;

    f32x4 acc[2][2] = {};

    for (int k0 = kz0; k0 < kz1; k0 += BK) {
        gl2lds16(gA0 + k0, lA0);
        gl2lds16(gA1 + k0, lA1);
        gl2lds16(gB0 + k0, lB0);
        gl2lds16(gB1 + k0, lB1);
        __syncthreads();

        bf16x8 af[2][2], bfr[2][2];     // [row-tile][k-step]
#pragma unroll
        for (int i = 0; i < 2; ++i)
#pragma unroll
            for (int u = 0; u < 2; ++u) {
                const int ak = u * 32 + fq * 8;
                af[i][u]  = *reinterpret_cast<const bf16x8*>(
                    sA + (wm + i * 16 + fr) * BK + ak);
                bfr[i][u] = *reinterpret_cast<const bf16x8*>(
                    sB + (wn + i * 16 + fr) * BK + ak);
            }
#pragma unroll
        for (int i = 0; i < 2; ++i)
#pragma unroll
            for (int j = 0; j < 2; ++j) {
                acc[i][j] = __builtin_amdgcn_mfma_f32_16x16x32_bf16(
                    af[i][0], bfr[j][0], acc[i][j], 0, 0, 0);
                acc[i][j] = __builtin_amdgcn_mfma_f32_16x16x32_bf16(
                    af[i][1], bfr[j][1], acc[i][j], 0, 0, 0);
            }
        __syncthreads();
    }

    const size_t zoff = (EPI == 0) ? (size_t)blockIdx.z * (size_t)M * N : 0;
#pragma unroll
    for (int j = 0; j < 2; ++j) {
        const int col = n0 + wn + j * 16 + fr;
        const float bv = (EPI == 1) ? bias[col] : 0.0f;
#pragma unroll
        for (int i = 0; i < 2; ++i) {
            const int rbase = m0 + wm + i * 16 + fq * 4;
#pragma unroll
            for (int r = 0; r < 4; ++r) {
                float v = acc[i][j][r] + bv;
                if (EPI == 1) v += rowterm[rbase + r];
                C[zoff + (size_t)(rbase + r) * N + col] = v;
            }
        }
    }
}

// ============ K3: reduce Y partials -> bf16 Y ===============================
__global__ __launch_bounds__(256) void reduce_y(
    const float* __restrict__ part, __bf16* __restrict__ Y) {
    const int i = blockIdx.x * blockDim.x + threadIdx.x;   // float4 idx
    const int n4 = 1024 * HIDDEN / 4;
    if (i >= n4) return;
    float4 s = {0, 0, 0, 0};
#pragma unroll
    for (int z = 0; z < ZY; ++z) {
        float4 p = reinterpret_cast<const float4*>(part + (size_t)z * 1024 * HIDDEN)[i];
        s.x += p.x; s.y += p.y; s.z += p.z; s.w += p.w;
    }
    bf16x4 o;
    o.x = (__bf16)s.x; o.y = (__bf16)s.y; o.z = (__bf16)s.z; o.w = (__bf16)s.w;
    reinterpret_cast<bf16x4*>(Y)[i] = o;
}

extern "C" void kernel_launch(void* const* d_in, const int* in_sizes, int n_in,
                              void* d_out, int out_size, void* d_ws, size_t ws_size,
                              hipStream_t stream) {
    const float* x        = (const float*)d_in[0];
    const float* codebook = (const float*)d_in[1];
    const float* w1       = (const float*)d_in[2];
    const float* b1       = (const float*)d_in[3];
    const float* w2       = (const float*)d_in[4];
    const float* b2       = (const float*)d_in[5];
    const float* bias     = (const float*)d_in[6];
    float* out = (float*)d_out;

    // ws layout (MB offsets):
    //   xb   bf16 256x4096       2 MB @ 0
    //   w2t  bf16 256x1024      .5 MB @ 2
    //   H    bf16 16384x256      8 MB @ 3
    //   Y    bf16 1024x256      .5 MB @ 11
    //   xb2  fp32 256            1 KB @ 12
    //   Yp   fp32 ZY x 1024x256  4 MB @ 13
    char* ws = (char*)d_ws;
    __bf16* xb  = (__bf16*)(ws);
    __bf16* w2t = (__bf16*)(ws + (2u << 20));
    __bf16* H   = (__bf16*)(ws + (3u << 20));
    __bf16* Y   = (__bf16*)(ws + (11u << 20));
    float*  xb2 = (float*)(ws + (12u << 20));
    float*  Yp  = (float*)(ws + (13u << 20));

    // K1: all prep (hidden + x-cvt/rowdot + w2 transpose)
    prep_kernel<<<1024, 256, 0, stream>>>(codebook, w1, b1, x, b2, w2,
                                          H, xb, xb2, w2t);

    // K2: Y partials = xr(1024x1024) @ w2t^T   (M=1024,N=256,K=1024), ZY-split
    {
        dim3 grid(HIDDEN / 64, 1024 / 64, ZY);   // 4 x 16 x 4 = 256 blocks
        gemm_bt_mfma64<0><<<grid, 256, 0, stream>>>(
            xb, w2t, nullptr, nullptr, Yp, 1024, HIDDEN, 1024, 1024 / ZY);
    }

    // K3: reduce Y partials -> bf16 Y
    reduce_y<<<(1024 * HIDDEN / 4) / 256, 256, 0, stream>>>(Yp, Y);

    // K4: out = Ycat(256x1024) @ Hflat^T + bias[col] + xb2[row]
    {
        dim3 grid(OUT_F / 64, TOKENS / 64, 1);   // 64 x 4 = 256 blocks
        gemm_bt_mfma64<1><<<grid, 256, 0, stream>>>(
            Y, H, bias, xb2, out, TOKENS, OUT_F, 1024, 1024);
    }
}

// Round 6
// 106.260 us; speedup vs baseline: 1.1533x; 1.0765x over previous
//
#include <hip/hip_runtime.h>
#include <math.h>

#define OUT_F      4096
#define IN_F       4096
#define NUM_CHUNKS 16384
#define CHUNK_SIZE 1024
#define D_ALPHA    64
#define HIDDEN     256
#define TOKENS     256

typedef __attribute__((ext_vector_type(8))) __bf16 bf16x8;
typedef __attribute__((ext_vector_type(4))) __bf16 bf16x4;
typedef __attribute__((ext_vector_type(4))) float f32x4;

__device__ __forceinline__ void gl2lds16(const void* g, void* l) {
    __builtin_amdgcn_global_load_lds(
        (const __attribute__((address_space(1))) void*)g,
        (__attribute__((address_space(3))) void*)l,
        16, 0, 0);
}

// ============ K1: fused prep ================================================
// blocks [0,1024)     : H = gelu(codebook @ w1^T + b1) via MFMA, 64x64 tile
// blocks [1024,1280)  : x fp32->bf16 + xb2[t] = dot(x[t], tile(b2))
// blocks [1280,1536)  : w2 (1024x256) -> w2t bf16 (256x1024)
__global__ __launch_bounds__(256) void prep_kernel(
    const float* __restrict__ cb, const float* __restrict__ w1,
    const float* __restrict__ b1, const float* __restrict__ x,
    const float* __restrict__ b2, const float* __restrict__ w2,
    __bf16* __restrict__ H, __bf16* __restrict__ xb,
    float* __restrict__ xb2, __bf16* __restrict__ w2t) {
    __shared__ char smem[16384];
    const int b   = blockIdx.x;
    const int tid = threadIdx.x;

    if (b < 1024) {
        // ---- hidden via MFMA: tile (by: 64 chunks) x (bx: 64 hidden), K=64
        const int by = b >> 2;
        const int bx = b & 3;
        const int c0 = by * 64, h0 = bx * 64;
        __bf16* sA = (__bf16*)smem;            // 64x64 bf16 (8 KB)
        __bf16* sB = (__bf16*)(smem + 8192);   // 64x64 bf16
        const float4* cb4 = reinterpret_cast<const float4*>(cb) + (size_t)by * 1024;
        const float4* w14 = reinterpret_cast<const float4*>(w1) + (size_t)bx * 1024;
#pragma unroll
        for (int q = 0; q < 4; ++q) {
            const int idx = q * 256 + tid;
            float4 va = cb4[idx];
            float4 vb = w14[idx];
            bf16x4 oa, ob;
            oa.x = (__bf16)va.x; oa.y = (__bf16)va.y; oa.z = (__bf16)va.z; oa.w = (__bf16)va.w;
            ob.x = (__bf16)vb.x; ob.y = (__bf16)vb.y; ob.z = (__bf16)vb.z; ob.w = (__bf16)vb.w;
            *reinterpret_cast<bf16x4*>(sA + idx * 4) = oa;
            *reinterpret_cast<bf16x4*>(sB + idx * 4) = ob;
        }
        __syncthreads();
        const int wave = tid >> 6, lane = tid & 63;
        const int wm = (wave & 1) * 32, wn = (wave >> 1) * 32;
        const int fr = lane & 15, fq = lane >> 4;
        f32x4 acc[2][2] = {};
        bf16x8 af[2][2], bv[2][2];
#pragma unroll
        for (int i = 0; i < 2; ++i)
#pragma unroll
            for (int u = 0; u < 2; ++u) {
                af[i][u] = *reinterpret_cast<const bf16x8*>(
                    sA + (wm + i * 16 + fr) * 64 + u * 32 + fq * 8);
                bv[i][u] = *reinterpret_cast<const bf16x8*>(
                    sB + (wn + i * 16 + fr) * 64 + u * 32 + fq * 8);
            }
#pragma unroll
        for (int u = 0; u < 2; ++u)
#pragma unroll
            for (int i = 0; i < 2; ++i)
#pragma unroll
                for (int j = 0; j < 2; ++j)
                    acc[i][j] = __builtin_amdgcn_mfma_f32_16x16x32_bf16(
                        af[i][u], bv[j][u], acc[i][j], 0, 0, 0);
#pragma unroll
        for (int j = 0; j < 2; ++j) {
            const int col = h0 + wn + j * 16 + fr;
            const float bb = b1[col];
#pragma unroll
            for (int i = 0; i < 2; ++i) {
                const int rbase = c0 + wm + i * 16 + fq * 4;
#pragma unroll
                for (int r = 0; r < 4; ++r) {
                    float v = acc[i][j][r] + bb;
                    float g = 0.5f * v * (1.0f + erff(v * 0.70710678118654752f));
                    H[(size_t)(rbase + r) * 256 + col] = (__bf16)g;
                }
            }
        }
    } else if (b < 1280) {
        // ---- x convert + row dot with tiled b2 ----
        float* ws_ = (float*)smem;
        const int t = b - 1024;
        const float4* xr  = reinterpret_cast<const float4*>(x + (size_t)t * IN_F);
        const float4* b24 = reinterpret_cast<const float4*>(b2);
        bf16x4* xb4 = reinterpret_cast<bf16x4*>(xb + (size_t)t * IN_F);
        float acc = 0.0f;
#pragma unroll
        for (int ii = 0; ii < 4; ++ii) {
            const int idx = ii * 256 + tid;
            float4 v = xr[idx];
            bf16x4 o;
            o.x = (__bf16)v.x; o.y = (__bf16)v.y; o.z = (__bf16)v.z; o.w = (__bf16)v.w;
            xb4[idx] = o;
            float4 bb = b24[idx & 255];
            acc += v.x * bb.x + v.y * bb.y + v.z * bb.z + v.w * bb.w;
        }
#pragma unroll
        for (int off = 32; off > 0; off >>= 1) acc += __shfl_down(acc, off, 64);
        if ((tid & 63) == 0) ws_[tid >> 6] = acc;
        __syncthreads();
        if (tid == 0) xb2[t] = ws_[0] + ws_[1] + ws_[2] + ws_[3];
    } else {
        // ---- w2 transpose -> bf16 ----
        float (*tile)[33] = (float (*)[33])smem;
        const int bb = b - 1280;
        const int h0 = (bb & 7) * 32;          // HIDDEN/32 = 8
        const int p0 = (bb >> 3) * 32;
        const int r = tid >> 5;
        const int c = tid & 31;
#pragma unroll
        for (int ii = 0; ii < 4; ++ii)
            tile[r + 8 * ii][c] = w2[(size_t)(p0 + r + 8 * ii) * HIDDEN + h0 + c];
        __syncthreads();
#pragma unroll
        for (int ii = 0; ii < 4; ++ii)
            w2t[(size_t)(h0 + r + 8 * ii) * CHUNK_SIZE + p0 + c] =
                (__bf16)tile[c][r + 8 * ii];
    }
}

// ============ bf16 MFMA GEMM, 64x64 tile, templated BK ======================
// C = A[M][K] @ B[N][K]^T ; 256 thr = 4 waves (2x2), wave 32x32 = 2x2 mfma.
// EPI 0: bf16 out, no bias.   EPI 1: fp32 out += bias[col] + rowterm[row].
template <int BK, int EPI>
__global__ __launch_bounds__(256) void gemm_bt64(
    const __bf16* __restrict__ A, const __bf16* __restrict__ B,
    const float* __restrict__ bias, const float* __restrict__ rowterm,
    void* __restrict__ Cv, int M, int N, int K) {
    __shared__ __bf16 sA[64 * BK];
    __shared__ __bf16 sB[64 * BK];
    const int tid = threadIdx.x;
    const int m0 = blockIdx.y * 64;
    const int n0 = blockIdx.x * 64;

    constexpr int NC = BK / 32;     // 16B staging chunks per thread per matrix
    int rowc[NC], colc[NC];
#pragma unroll
    for (int c = 0; c < NC; ++c) {
        const int flat = c * 2048 + tid * 8;
        rowc[c] = flat / BK;
        colc[c] = flat % BK;
    }

    const int wave = tid >> 6, lane = tid & 63;
    const int wm = (wave & 1) * 32, wn = (wave >> 1) * 32;
    const int fr = lane & 15, fq = lane >> 4;

    f32x4 acc[2][2] = {};

    for (int k0 = 0; k0 < K; k0 += BK) {
#pragma unroll
        for (int c = 0; c < NC; ++c) {
            gl2lds16(A + (size_t)(m0 + rowc[c]) * K + k0 + colc[c],
                     sA + c * 2048 + tid * 8);
            gl2lds16(B + (size_t)(n0 + rowc[c]) * K + k0 + colc[c],
                     sB + c * 2048 + tid * 8);
        }
        __syncthreads();

#pragma unroll
        for (int u = 0; u < BK / 32; ++u) {
            bf16x8 af[2], bv[2];
#pragma unroll
            for (int i = 0; i < 2; ++i) {
                af[i] = *reinterpret_cast<const bf16x8*>(
                    sA + (wm + i * 16 + fr) * BK + u * 32 + fq * 8);
                bv[i] = *reinterpret_cast<const bf16x8*>(
                    sB + (wn + i * 16 + fr) * BK + u * 32 + fq * 8);
            }
#pragma unroll
            for (int i = 0; i < 2; ++i)
#pragma unroll
                for (int j = 0; j < 2; ++j)
                    acc[i][j] = __builtin_amdgcn_mfma_f32_16x16x32_bf16(
                        af[i], bv[j], acc[i][j], 0, 0, 0);
        }
        __syncthreads();
    }

    if (EPI == 0) {
        __bf16* C = (__bf16*)Cv;
#pragma unroll
        for (int j = 0; j < 2; ++j) {
            const int col = n0 + wn + j * 16 + fr;
#pragma unroll
            for (int i = 0; i < 2; ++i) {
                const int rbase = m0 + wm + i * 16 + fq * 4;
#pragma unroll
                for (int r = 0; r < 4; ++r)
                    C[(size_t)(rbase + r) * N + col] = (__bf16)acc[i][j][r];
            }
        }
    } else {
        float* C = (float*)Cv;
#pragma unroll
        for (int j = 0; j < 2; ++j) {
            const int col = n0 + wn + j * 16 + fr;
            const float bvs = bias[col];
#pragma unroll
            for (int i = 0; i < 2; ++i) {
                const int rbase = m0 + wm + i * 16 + fq * 4;
#pragma unroll
                for (int r = 0; r < 4; ++r)
                    C[(size_t)(rbase + r) * N + col] =
                        acc[i][j][r] + bvs + rowterm[rbase + r];
            }
        }
    }
}

extern "C" void kernel_launch(void* const* d_in, const int* in_sizes, int n_in,
                              void* d_out, int out_size, void* d_ws, size_t ws_size,
                              hipStream_t stream) {
    const float* x        = (const float*)d_in[0];
    const float* codebook = (const float*)d_in[1];
    const float* w1       = (const float*)d_in[2];
    const float* b1       = (const float*)d_in[3];
    const float* w2       = (const float*)d_in[4];
    const float* b2       = (const float*)d_in[5];
    const float* bias     = (const float*)d_in[6];
    float* out = (float*)d_out;

    // ws layout (MB offsets):
    //   xb   bf16 256x4096   2 MB @ 0
    //   w2t  bf16 256x1024  .5 MB @ 2
    //   H    bf16 16384x256  8 MB @ 3
    //   Y    bf16 1024x256  .5 MB @ 11
    //   xb2  fp32 256        1 KB @ 12
    char* ws = (char*)d_ws;
    __bf16* xb  = (__bf16*)(ws);
    __bf16* w2t = (__bf16*)(ws + (2u << 20));
    __bf16* H   = (__bf16*)(ws + (3u << 20));
    __bf16* Y   = (__bf16*)(ws + (11u << 20));
    float*  xb2 = (float*)(ws + (12u << 20));

    // K1: all prep (hidden-MFMA + x-cvt/rowdot + w2 transpose)
    prep_kernel<<<1536, 256, 0, stream>>>(codebook, w1, b1, x, b2, w2,
                                          H, xb, xb2, w2t);

    // K2: Y = xr(1024x1024) @ w2t^T -> bf16   (M=1024, N=256, K=1024)
    {
        dim3 grid(HIDDEN / 64, 1024 / 64, 1);    // 4 x 16 = 64 blocks
        gemm_bt64<128, 0><<<grid, 256, 0, stream>>>(
            xb, w2t, nullptr, nullptr, Y, 1024, HIDDEN, 1024);
    }

    // K3: out = Ycat(256x1024) @ Hflat^T + bias[col] + xb2[row]
    {
        dim3 grid(OUT_F / 64, TOKENS / 64, 1);   // 64 x 4 = 256 blocks
        gemm_bt64<128, 1><<<grid, 256, 0, stream>>>(
            Y, H, bias, xb2, out, TOKENS, OUT_F, 1024);
    }
}